// Round 11
// baseline (418.246 us; speedup 1.0000x reference)
//
#include <hip/hip_runtime.h>

typedef unsigned short u16;
typedef unsigned int   u32;

using v8s = __attribute__((ext_vector_type(8))) short;
using v4f = __attribute__((ext_vector_type(4))) float;

__device__ __forceinline__ float b2f(u16 u){ union{u32 i; float f;} x; x.i=((u32)u)<<16; return x.f; }
__device__ __forceinline__ float blo(u32 u){ union{u32 i; float f;} x; x.i=u<<16; return x.f; }
__device__ __forceinline__ float bhi(u32 u){ union{u32 i; float f;} x; x.i=u&0xffff0000u; return x.f; }
// round-half-up bf16: 0.5-ULP bound like RNE, 2 VALU ops instead of ~9
__device__ __forceinline__ u16 f2b(float f){ union{float f; u32 i;} x; x.f=f; return (u16)((x.i + 0x8000u)>>16); }
__device__ __forceinline__ u32 f2b2(float a,float b){ return (u32)f2b(a) | ((u32)f2b(b)<<16); }

// hardware 2^x (v_exp_f32) with constant pre-fold; rcp instead of IEEE divide
#if __has_builtin(__builtin_amdgcn_exp2f)
__device__ __forceinline__ float ex2(float x){ return __builtin_amdgcn_exp2f(x); }
#else
__device__ __forceinline__ float ex2(float x){ return __expf(x * 0.69314718055994531f); }
#endif
#if __has_builtin(__builtin_amdgcn_rcpf)
__device__ __forceinline__ float frcp(float x){ return __builtin_amdgcn_rcpf(x); }
#else
__device__ __forceinline__ float frcp(float x){ return 1.f/x; }
#endif
#define SC2E 0.25503486f            /* (1/sqrt(32)) * log2(e) */
#define L2E  1.4426950408889634f    /* log2(e) */

#define MFMA(a,b,c) __builtin_amdgcn_mfma_f32_16x16x32_bf16(a,b,c,0,0,0)

// ---------------------------------------------------------------------------
// f32 -> bf16 converters
// ---------------------------------------------------------------------------
__global__ __launch_bounds__(256)
void cvt_f32(const float* __restrict__ src, u16* __restrict__ dst, u32 n4)
{ // n4 = n/4; each thread converts 4
  u32 i = blockIdx.x*256 + threadIdx.x;
  if (i >= n4) return;
  const float4 v = *(const float4*)(src + (size_t)i*4);
  uint2 o = { f2b2(v.x, v.y), f2b2(v.z, v.w) };
  *(uint2*)(dst + (size_t)i*4) = o;
}

struct Segs { const void* src[26]; u32 off[26]; u32 n[26]; };

__global__ __launch_bounds__(256)
void cvt_segs(Segs s, u16* __restrict__ dst)
{
  u32 stride = gridDim.x * 256;
  u32 gid = blockIdx.x*256 + threadIdx.x;
  for (int k = 0; k < 26; k++) {
    const float* sf = (const float*)s.src[k];
    u16* d = dst + s.off[k];
    for (u32 i = gid; i < s.n[k]; i += stride) d[i] = f2b(sf[i]);
  }
}

// ---------------------------------------------------------------------------
// Generic GEMM: C[M,N] = A[M,K] @ B[N,K]^T + bias.  All bf16.  MODE 0 only.
// Wave computes a 32x64 tile. Transposed MFMA (operands swapped) so each
// lane's 4 acc regs are 4 CONSECUTIVE output columns -> packed 8B stores.
// ---------------------------------------------------------------------------
template<int K, int MODE>
__global__ __launch_bounds__(256)
void gemm_t(const u16* __restrict__ A, const u16* __restrict__ B,
            const u16* __restrict__ bias, u16* __restrict__ C,
            int M, int N)
{
  int wid = threadIdx.x >> 6, lane = threadIdx.x & 63;
  int tiles_n = N >> 6;
  int t = blockIdx.x*4 + wid;
  if (t >= (M>>5)*tiles_n) return;
  int tm = t / tiles_n, tn = t % tiles_n;
  int m0 = tm<<5, n0 = tn<<6;
  int lr = lane & 15, ko = (lane>>4)<<3;
  const u16* ap = A + (size_t)(m0+lr)*K + ko;
  const u16* bp = B + (size_t)(n0+lr)*K + ko;
  v4f acc[2][4];
  #pragma unroll
  for (int x=0;x<2;x++)
    #pragma unroll
    for (int y=0;y<4;y++){ v4f z={0.f,0.f,0.f,0.f}; acc[x][y]=z; }
  #pragma unroll
  for (int kc = 0; kc < K; kc += 32) {
    v8s a0 = *(const v8s*)(ap + kc);
    v8s a1 = *(const v8s*)(ap + (size_t)16*K + kc);
    #pragma unroll
    for (int y=0;y<4;y++){
      v8s b = *(const v8s*)(bp + (size_t)(y<<4)*K + kc);
      acc[0][y]=MFMA(b,a0,acc[0][y]);   // transposed: D'[n][m]
      acc[1][y]=MFMA(b,a1,acc[1][y]);
    }
  }
  // D' layout: acc[x][y][r] = C[row = m0+x*16+cl][col = n0+y*16+rq+r]
  int cl = lane&15, rq=(lane>>4)<<2;
  #pragma unroll
  for (int y=0;y<4;y++){
    u32 bl = *(const u32*)(bias + n0 + (y<<4) + rq);
    u32 bh = *(const u32*)(bias + n0 + (y<<4) + rq + 2);
    float bv0=blo(bl), bv1=bhi(bl), bv2=blo(bh), bv3=bhi(bh);
    #pragma unroll
    for (int x=0;x<2;x++){
      float v0 = acc[x][y][0] + bv0;
      float v1 = acc[x][y][1] + bv1;
      float v2 = acc[x][y][2] + bv2;
      float v3 = acc[x][y][3] + bv3;
      uint2 pk = { f2b2(v0,v1), f2b2(v2,v3) };
      int row = m0 + (x<<4) + cl;
      int col = n0 + (y<<4) + rq;         // 4-aligned
      *(uint2*)&C[(size_t)row*N + col] = pk;
    }
  }
}

// ---------------------------------------------------------------------------
// Fused GEMM(8192x256, K=256) + LayerNorm over the 256-col rows.
// ---------------------------------------------------------------------------
template<int F32OUT>
__global__ __launch_bounds__(256)
void gemm_ln256(const u16* __restrict__ A, const u16* __restrict__ B,
                const u16* __restrict__ bias, const u16* __restrict__ gg,
                const u16* __restrict__ bb, void* __restrict__ Yv)
{
  int wid = threadIdx.x >> 6, lane = threadIdx.x & 63;
  int m0 = blockIdx.x << 5, n0 = wid << 6;
  int lr = lane & 15, ko = (lane>>4)<<3;
  const u16* ap = A + (size_t)(m0+lr)*256 + ko;
  const u16* bp = B + (size_t)(n0+lr)*256 + ko;
  v4f acc[2][4];
  #pragma unroll
  for (int x=0;x<2;x++)
    #pragma unroll
    for (int y=0;y<4;y++){ v4f z={0.f,0.f,0.f,0.f}; acc[x][y]=z; }
  #pragma unroll
  for (int kc = 0; kc < 256; kc += 32) {
    v8s a0 = *(const v8s*)(ap + kc);
    v8s a1 = *(const v8s*)(ap + (size_t)16*256 + kc);
    #pragma unroll
    for (int y=0;y<4;y++){
      v8s b = *(const v8s*)(bp + (size_t)(y<<4)*256 + kc);
      acc[0][y]=MFMA(b,a0,acc[0][y]);
      acc[1][y]=MFMA(b,a1,acc[1][y]);
    }
  }
  int cl = lane&15, rq=(lane>>4)<<2;
  __shared__ alignas(16) u16 stage[32][264];   // padded: ~2-way banks
  #pragma unroll
  for (int y=0;y<4;y++){
    u32 bl = *(const u32*)(bias + n0 + (y<<4) + rq);
    u32 bh = *(const u32*)(bias + n0 + (y<<4) + rq + 2);
    float bv0=blo(bl), bv1=bhi(bl), bv2=blo(bh), bv3=bhi(bh);
    #pragma unroll
    for (int x=0;x<2;x++){
      uint2 pk = { f2b2(acc[x][y][0]+bv0, acc[x][y][1]+bv1),
                   f2b2(acc[x][y][2]+bv2, acc[x][y][3]+bv3) };
      *(uint2*)&stage[(x<<4)+cl][n0 + (y<<4) + rq] = pk;
    }
  }
  __syncthreads();
  // LN: wave handles rows wid*8 .. wid*8+7 (identical math to ln256)
  for (int rr = 0; rr < 8; rr++){
    int row = wid*8 + rr;
    u32 a = *(const u32*)&stage[row][lane*2];
    u32 c = *(const u32*)&stage[row][128 + lane*2];
    float v0=blo(a), v1=bhi(a), v2=blo(c), v3=bhi(c);
    float s = v0+v1+v2+v3;
    for (int m=1;m<64;m<<=1) s += __shfl_xor(s,m,64);
    float mean = s * (1.f/256.f);
    float d0=v0-mean,d1=v1-mean,d2=v2-mean,d3=v3-mean;
    float qs = d0*d0+d1*d1+d2*d2+d3*d3;
    for (int m=1;m<64;m<<=1) qs += __shfl_xor(qs,m,64);
    float rstd = rsqrtf(qs*(1.f/256.f) + 1e-5f);
    u32 g0=*(const u32*)(gg+lane*2), g1=*(const u32*)(gg+128+lane*2);
    u32 b0=*(const u32*)(bb+lane*2), b1=*(const u32*)(bb+128+lane*2);
    float w0 = d0*rstd*blo(g0)+blo(b0), w1 = d1*rstd*bhi(g0)+bhi(b0);
    float w2 = d2*rstd*blo(g1)+blo(b1), w3 = d3*rstd*bhi(g1)+bhi(b1);
    if (F32OUT){
      float* y = (float*)Yv + (size_t)(m0+row)*256;
      float2 p0 = {w0,w1}, p1 = {w2,w3};
      *(float2*)(y + lane*2)       = p0;
      *(float2*)(y + 128 + lane*2) = p1;
    } else {
      u16* y = (u16*)Yv + (size_t)(m0+row)*256;
      *(u32*)(y+lane*2)     = f2b2(w0,w1);
      *(u32*)(y+128+lane*2) = f2b2(w2,w3);
    }
  }
}

// ---------------------------------------------------------------------------
// Fused GEMM(65536x128, K=128) + residual LayerNorm (X + R) -> f32 out_pair.
// ---------------------------------------------------------------------------
__global__ __launch_bounds__(256)
void gemm_ln128_res(const u16* __restrict__ A, const u16* __restrict__ B,
                    const u16* __restrict__ bias, const u16* __restrict__ R,
                    const u16* __restrict__ gg, const u16* __restrict__ bb,
                    float* __restrict__ Y)
{
  int wid = threadIdx.x >> 6, lane = threadIdx.x & 63;
  int t = blockIdx.x*4 + wid;          // 4096 total, exact
  int tm = t >> 1, tn = t & 1;
  int m0 = tm << 5, n0 = tn << 6;
  int mB = blockIdx.x << 6;            // block row base (64 rows)
  int lr = lane & 15, ko = (lane>>4)<<3;
  const u16* ap = A + (size_t)(m0+lr)*128 + ko;
  const u16* bp = B + (size_t)(n0+lr)*128 + ko;
  v4f acc[2][4];
  #pragma unroll
  for (int x=0;x<2;x++)
    #pragma unroll
    for (int y=0;y<4;y++){ v4f z={0.f,0.f,0.f,0.f}; acc[x][y]=z; }
  #pragma unroll
  for (int kc = 0; kc < 128; kc += 32) {
    v8s a0 = *(const v8s*)(ap + kc);
    v8s a1 = *(const v8s*)(ap + (size_t)16*128 + kc);
    #pragma unroll
    for (int y=0;y<4;y++){
      v8s b = *(const v8s*)(bp + (size_t)(y<<4)*128 + kc);
      acc[0][y]=MFMA(b,a0,acc[0][y]);
      acc[1][y]=MFMA(b,a1,acc[1][y]);
    }
  }
  int cl = lane&15, rq=(lane>>4)<<2;
  __shared__ alignas(16) u16 stage[64][136];   // padded: ~2-way banks
  int rbase = m0 - mB;                         // 0 or 32
  #pragma unroll
  for (int y=0;y<4;y++){
    u32 bl = *(const u32*)(bias + n0 + (y<<4) + rq);
    u32 bh = *(const u32*)(bias + n0 + (y<<4) + rq + 2);
    float bv0=blo(bl), bv1=bhi(bl), bv2=blo(bh), bv3=bhi(bh);
    #pragma unroll
    for (int x=0;x<2;x++){
      uint2 pk = { f2b2(acc[x][y][0]+bv0, acc[x][y][1]+bv1),
                   f2b2(acc[x][y][2]+bv2, acc[x][y][3]+bv3) };
      *(uint2*)&stage[rbase + (x<<4)+cl][n0 + (y<<4) + rq] = pk;
    }
  }
  __syncthreads();
  // LN(X+R): wave handles rows wid*16 .. wid*16+15 (identical to ln_res128_f32)
  for (int rr = 0; rr < 16; rr++){
    int r_loc = wid*16 + rr;
    int row = mB + r_loc;
    u32 ux = *(const u32*)&stage[r_loc][lane*2];
    u32 ur = *(const u32*)(R + (size_t)row*128 + lane*2);
    float v0 = blo(ux)+blo(ur), v1 = bhi(ux)+bhi(ur);
    float s = v0+v1;
    for (int m=1;m<64;m<<=1) s += __shfl_xor(s,m,64);
    float mean = s * (1.f/128.f);
    float d0=v0-mean, d1=v1-mean;
    float qs = d0*d0+d1*d1;
    for (int m=1;m<64;m<<=1) qs += __shfl_xor(qs,m,64);
    float rstd = rsqrtf(qs*(1.f/128.f)+1e-5f);
    u32 ug = *(const u32*)(gg + lane*2), ub = *(const u32*)(bb + lane*2);
    float2 w = { d0*rstd*blo(ug)+blo(ub), d1*rstd*bhi(ug)+bhi(ub) };
    *(float2*)&Y[(size_t)row*128 + lane*2] = w;
  }
}

// ---------------------------------------------------------------------------
// Triangle projection GEMM: C[r][col] = pairT[r][:] @ Wall[col][:]^T + ball.
// Block = 128 rows; wave = 32 rows, A register-cached, loops all 8 col-tiles.
// K-group output (gg 4..7) is PRE-SCALED by SC2E so tri_pass1/2 compute
// exp2(s) with no per-element scale mul (same 1-rounding error structure).
// ---------------------------------------------------------------------------
__global__ __launch_bounds__(256)
void tri_proj(const u16* __restrict__ A, const u16* __restrict__ B,
              const u16* __restrict__ bias, u16* __restrict__ C)
{
  int wid = threadIdx.x >> 6, lane = threadIdx.x & 63;
  int r0 = blockIdx.x << 7;            // 128 rows per block (512 blocks)
  int rw = r0 + (wid << 5);            // wave rows rw..rw+31
  int lr = lane & 15, ko = (lane>>4)<<3;
  int cl = lane & 15, rq = (lane>>4)<<2;
  int n  = r0 >> 8;                    // n-chunk (block never straddles)
  int j0 = rw & 255;                   // token base within chunk
  // preload A (32 rows x 128) into regs: 2 row-groups x 4 k-chunks
  const u16* ap = A + (size_t)(rw + lr)*128 + ko;
  v8s av[2][4];
  #pragma unroll
  for (int xg=0;xg<2;xg++)
    #pragma unroll
    for (int kq=0;kq<4;kq++)
      av[xg][kq] = *(const v8s*)(ap + (size_t)(xg<<4)*128 + (kq<<5));
  __shared__ alignas(16) u16 stg[4][2][32][40];   // padded rows (20 KB)
  for (int tn=0; tn<8; tn++){
    int n0 = tn<<6;
    const u16* bp = B + (size_t)(n0 + lr)*128 + ko;
    v8s bv[4][4];
    #pragma unroll
    for (int y=0;y<4;y++)
      #pragma unroll
      for (int kq=0;kq<4;kq++)
        bv[y][kq] = *(const v8s*)(bp + (size_t)(y<<4)*128 + (kq<<5));
    v4f acc[2][4];
    #pragma unroll
    for (int xg=0;xg<2;xg++)
      #pragma unroll
      for (int y=0;y<4;y++){ v4f z={0.f,0.f,0.f,0.f}; acc[xg][y]=z; }
    #pragma unroll
    for (int kq=0;kq<4;kq++)
      #pragma unroll
      for (int xg=0;xg<2;xg++)
        #pragma unroll
        for (int y=0;y<4;y++)
          acc[xg][y] = MFMA(bv[y][kq], av[xg][kq], acc[xg][y]);  // D'[col][row]
    // acc[xg][y][r] = C[row = rw + xg*16 + cl][col = n0 + y*16 + rq + r]
    #pragma unroll
    for (int g2=0; g2<2; g2++){
      int gg = (n0>>5) + g2;
      bool isV = (gg>=8) && (gg<12);
      bool isK = (gg>=4) && (gg<8);
      float scl = isK ? SC2E : 1.f;
      u16* sw = &stg[wid][g2][0][0];
      #pragma unroll
      for (int yy=0; yy<2; yy++){
        int y = (g2<<1)+yy;
        u32 bl2 = *(const u32*)(bias + n0 + (y<<4) + rq);
        u32 bh2 = *(const u32*)(bias + n0 + (y<<4) + rq + 2);
        float bb0=blo(bl2), bb1=bhi(bl2), bb2=blo(bh2), bb3=bhi(bh2);
        #pragma unroll
        for (int xg=0;xg<2;xg++){
          float v0=(acc[xg][y][0]+bb0)*scl, v1=(acc[xg][y][1]+bb1)*scl;
          float v2=(acc[xg][y][2]+bb2)*scl, v3=(acc[xg][y][3]+bb3)*scl;
          int tok=(xg<<4)+cl, cb=(yy<<4)+rq;
          if (!isV){
            uint2 pk = { f2b2(v0,v1), f2b2(v2,v3) };
            *(uint2*)(sw + tok*40 + cb) = pk;        // [tok][c]
          } else {
            sw[(cb+0)*40+tok]=f2b(v0);               // [c][tok] (transpose)
            sw[(cb+1)*40+tok]=f2b(v1);
            sw[(cb+2)*40+tok]=f2b(v2);
            sw[(cb+3)*40+tok]=f2b(v3);
          }
        }
      }
      // wave-internal LDS RAW: backend inserts lgkmcnt wait (same object)
      if (!isV){
        u16* dst = C + (size_t)gg*2097152 + (size_t)rw*32;   // 2KB contiguous
        #pragma unroll
        for (int q=0;q<2;q++){
          int row = (q<<4) + (lane>>2), c8 = (lane&3)<<3;
          uint4 d = *(const uint4*)(sw + row*40 + c8);
          *(uint4*)(dst + (q<<9) + (lane<<3)) = d;
        }
      } else {
        int cr0 = lane>>2, off=(lane&3)<<3;
        #pragma unroll
        for (int q=0;q<2;q++){
          int cr = (q<<4)+cr0;
          uint4 d = *(const uint4*)(sw + cr*40 + off);
          *(uint4*)(C + (size_t)gg*2097152 + ((size_t)n<<13) + ((size_t)cr<<8) + j0 + off) = d;
        }
      }
    }
  }
}

// ---------------------------------------------------------------------------
// Row attention core: block = (bs,h,si). Input QKV [8192][768] (Q|K|V of 256).
// ---------------------------------------------------------------------------
__global__ __launch_bounds__(256)
void row_attn(const u16* __restrict__ QKV, u16* __restrict__ Out)
{
  int si = blockIdx.x & 3, h = (blockIdx.x>>2) & 7, bs = blockIdx.x >> 5;
  int wid = threadIdx.x >> 6, lane = threadIdx.x & 63;
  int lr = lane & 15, ko = (lane>>4)<<3;
  int cl = lane & 15, rq = (lane>>4)<<2;
  __shared__ alignas(16) u16 VtS[32][264];      // V^T  [c][j]
  __shared__ alignas(16) u16 AsS[4][16][264];   // per-wave attn strip [i][j]
  const u16* base = QKV + (size_t)bs * 256 * 768;
  for (int e = threadIdx.x; e < 4096; e += 256) {
    int j = e >> 4, cu = e & 15;
    u32 v = *(const u32*)(base + (size_t)j*768 + 512 + h*32 + cu*2);
    VtS[cu*2][j]   = (u16)(v & 0xffffu);
    VtS[cu*2+1][j] = (u16)(v >> 16);
  }
  __syncthreads();
  int i0 = si*64 + wid*16;
  v8s a = *(const v8s*)(base + (size_t)(i0+lr)*768 + h*32 + ko);
  v4f s[16];
  #pragma unroll
  for (int jt = 0; jt < 16; jt++) {
    v8s b = *(const v8s*)(base + (size_t)(jt*16+lr)*768 + 256 + h*32 + ko);
    v4f z = {0.f,0.f,0.f,0.f};
    s[jt] = MFMA(a, b, z);
  }
  float part[4] = {0.f,0.f,0.f,0.f};
  #pragma unroll
  for (int jt = 0; jt < 16; jt++)
    #pragma unroll
    for (int r = 0; r < 4; r++) {
      float e = ex2(s[jt][r] * SC2E);
      s[jt][r] = e;
      part[r] += e;
    }
  #pragma unroll
  for (int r = 0; r < 4; r++) {
    part[r] += __shfl_xor(part[r], 1, 64);
    part[r] += __shfl_xor(part[r], 2, 64);
    part[r] += __shfl_xor(part[r], 4, 64);
    part[r] += __shfl_xor(part[r], 8, 64);
    part[r] = frcp(part[r]);
  }
  #pragma unroll
  for (int jt = 0; jt < 16; jt++)
    #pragma unroll
    for (int r = 0; r < 4; r++)
      AsS[wid][rq+r][jt*16+cl] = f2b(s[jt][r] * part[r]);
  __syncthreads();
  v4f o0={0.f,0.f,0.f,0.f}, o1={0.f,0.f,0.f,0.f};
  #pragma unroll
  for (int kc = 0; kc < 8; kc++) {
    v8s av = *(const v8s*)&AsS[wid][lr][kc*32 + ko];
    v8s b0 = *(const v8s*)&VtS[lr][kc*32 + ko];
    v8s b1 = *(const v8s*)&VtS[16+lr][kc*32 + ko];
    o0 = MFMA(av, b0, o0);
    o1 = MFMA(av, b1, o1);
  }
  u16* orow = Out + ((size_t)(bs*256) + i0)*256 + h*32;
  #pragma unroll
  for (int r = 0; r < 4; r++) {
    orow[(size_t)(rq+r)*256 + cl]      = f2b(o0[r]);
    orow[(size_t)(rq+r)*256 + 16 + cl] = f2b(o1[r]);
  }
}

// ---------------------------------------------------------------------------
// Column attention core: block = n. 32 tokens (s axis), 8 heads. thread=(h,i).
// ---------------------------------------------------------------------------
__global__ __launch_bounds__(256)
void col_attn(const u16* __restrict__ QKV, u16* __restrict__ Out)
{
  int n = blockIdx.x;
  __shared__ alignas(16) u16 T[32][776];
  for (int e = threadIdx.x; e < 32*384; e += 256) {
    int s = e / 384, u = e % 384;
    *(u32*)&T[s][u*2] = *(const u32*)(QKV + ((size_t)s*256 + n)*768 + u*2);
  }
  __syncthreads();
  int h = threadIdx.x >> 5, i = threadIdx.x & 31;
  float q[32];
  #pragma unroll
  for (int cu = 0; cu < 4; cu++) {
    v8s qv = *(const v8s*)&T[i][h*32 + cu*8];
    #pragma unroll
    for (int t2 = 0; t2 < 8; t2++) q[cu*8+t2] = b2f((u16)qv[t2]);
  }
  float sj[32];
  float Z = 0.f;
  #pragma unroll 4
  for (int j = 0; j < 32; j++) {
    float acc = 0.f;
    #pragma unroll
    for (int cu = 0; cu < 4; cu++) {
      v8s kv = *(const v8s*)&T[j][256 + h*32 + cu*8];
      #pragma unroll
      for (int t2 = 0; t2 < 8; t2++) acc += q[cu*8+t2] * b2f((u16)kv[t2]);
    }
    sj[j] = ex2(acc * SC2E);
    Z += sj[j];
  }
  float zi = frcp(Z);
  float o[32];
  #pragma unroll
  for (int c = 0; c < 32; c++) o[c] = 0.f;
  #pragma unroll 4
  for (int j = 0; j < 32; j++) {
    float a = sj[j] * zi;
    #pragma unroll
    for (int cu = 0; cu < 4; cu++) {
      v8s vv = *(const v8s*)&T[j][512 + h*32 + cu*8];
      #pragma unroll
      for (int t2 = 0; t2 < 8; t2++) o[cu*8+t2] += a * b2f((u16)vv[t2]);
    }
  }
  u16* orow = Out + ((size_t)i*256 + n)*256 + h*32;
  #pragma unroll
  for (int cu = 0; cu < 16; cu++)
    *(u32*)&orow[cu*2] = f2b2(o[cu*2], o[cu*2+1]);
}

// ---------------------------------------------------------------------------
// mean over s of final msa (f32) -> Mean[n][c] bf16
// ---------------------------------------------------------------------------
__global__ __launch_bounds__(256)
void mean_rows(const float* __restrict__ M2, u16* __restrict__ Mean)
{
  int n = blockIdx.x, c = threadIdx.x;
  float s = 0.f;
  for (int ss = 0; ss < 32; ss++) s += M2[((size_t)ss*256 + n)*256 + c];
  Mean[(size_t)n*256 + c] = f2b(s * 0.03125f);
}

// ---------------------------------------------------------------------------
// pairN = LN(pair_f32 + outer(left,left)). wave per row (i,j). bf16 out.
// Also writes pairT[j*256+i] (transposed copy) for the projection GEMM.
// ---------------------------------------------------------------------------
__global__ __launch_bounds__(256)
void pair_outer_ln(const float* __restrict__ Pair, const u16* __restrict__ Left,
                   const u16* __restrict__ gg, const u16* __restrict__ bb,
                   u16* __restrict__ PairN, u16* __restrict__ PairT)
{
  int row = blockIdx.x*4 + (threadIdx.x>>6), lane = threadIdx.x & 63;
  int i = row >> 8, j = row & 255;
  float p0 = Pair[(size_t)row*128 + lane*2];
  float p1 = Pair[(size_t)row*128 + lane*2 + 1];
  u32 ul = *(const u32*)(Left + (size_t)i*128 + lane*2);
  u32 ur = *(const u32*)(Left + (size_t)j*128 + lane*2);
  float v0 = p0 + blo(ul)*blo(ur);
  float v1 = p1 + bhi(ul)*bhi(ur);
  float s = v0+v1;
  for (int m=1;m<64;m<<=1) s += __shfl_xor(s,m,64);
  float mean = s * (1.f/128.f);
  float d0=v0-mean, d1=v1-mean;
  float qs = d0*d0+d1*d1;
  for (int m=1;m<64;m<<=1) qs += __shfl_xor(qs,m,64);
  float rstd = rsqrtf(qs*(1.f/128.f)+1e-5f);
  u32 ug = *(const u32*)(gg + lane*2), ub = *(const u32*)(bb + lane*2);
  u32 pk = f2b2(d0*rstd*blo(ug)+blo(ub), d1*rstd*bhi(ug)+bhi(ub));
  *(u32*)&PairN[(size_t)row*128 + lane*2] = pk;
  *(u32*)&PairT[((size_t)j*256 + i)*128 + lane*2] = pk;
}

// ---------------------------------------------------------------------------
// Pack combined triangle weights: Wall[512][128]; ball[512].
// ---------------------------------------------------------------------------
__global__ __launch_bounds__(256)
void pack_w(const u16* __restrict__ tq_W, const u16* __restrict__ tk_W,
            const u16* __restrict__ tv_W, const u16* __restrict__ tg_W,
            const u16* __restrict__ tq_b, const u16* __restrict__ tk_b,
            const u16* __restrict__ tv_b, const u16* __restrict__ tg_b,
            u16* __restrict__ Wall, u16* __restrict__ ball)
{
  int idx = blockIdx.x*256 + threadIdx.x;   // 65536 total
  int r = idx>>7, c = idx&127;
  int part = r>>7, hr = r&127;
  const u16* W = (part==0)? tq_W : (part==1)? tk_W : (part==2)? tv_W : tg_W;
  Wall[idx] = W[(size_t)hr*128 + c];
  if (idx < 512) {
    int p2 = idx>>7, hr2 = idx&127;
    const u16* bsrc = (p2==0)? tq_b : (p2==1)? tk_b : (p2==2)? tv_b : tg_b;
    ball[idx] = bsrc[hr2];
  }
}

// ---------------------------------------------------------------------------
// Triangle pass 1 (all heads): Zp[h][nh][i][j] = sum_{n in chunk} exp2(q·k')
// (K pre-scaled by SC2E at tri_proj -> no per-element scale mul here.)
// ---------------------------------------------------------------------------
__global__ __launch_bounds__(256)
void tri_pass1(const u16* __restrict__ Qall, const u16* __restrict__ Kall,
               float* __restrict__ Zp)
{
  int wid = threadIdx.x>>6, lane = threadIdx.x&63;
  int bx = blockIdx.x;
  int jb = bx & 3, it = (bx>>2)&15, nh = (bx>>6)&7, h = bx>>9;
  int i0 = it<<4, j0 = (jb<<6) + (wid<<4);
  int lr = lane&15, ko=(lane>>4)<<3;
  const u16* qp = Qall + (size_t)h*2097152 + ((size_t)(nh<<5)*256 + i0 + lr)*32 + ko;
  const u16* kp = Kall + (size_t)h*2097152 + ((size_t)(nh<<5)*256 + j0 + lr)*32 + ko;
  float Z[4] = {0.f,0.f,0.f,0.f};
  #pragma unroll
  for (int g=0;g<4;g++){
    v8s qa[8], kb[8];
    #pragma unroll
    for (int t=0;t<8;t++){
      qa[t] = *(const v8s*)(qp + (size_t)(g*8+t)*8192);
      kb[t] = *(const v8s*)(kp + (size_t)(g*8+t)*8192);
    }
    #pragma unroll
    for (int t=0;t<8;t++){
      v4f z = {0.f,0.f,0.f,0.f};
      v4f s = MFMA(qa[t],kb[t],z);
      #pragma unroll
      for (int r=0;r<4;r++) Z[r] += ex2(s[r]);
    }
  }
  int cl=lane&15, rq=(lane>>4)<<2;
  float* zr = Zp + ((size_t)h<<19) + ((size_t)nh<<16);
  #pragma unroll
  for (int r=0;r<4;r++)
    zr[(size_t)(i0+rq+r)*256 + j0+cl] = Z[r];
}

// Zi16[h][ij] = bf16( 1 / sum_nh Zp[h][nh][ij] )  (bf16 halves tri_pass2's
// zi register footprint: 64 -> 32 VGPRs -> under the 64-VGPR occupancy step)
__global__ __launch_bounds__(256)
void zred(const float* __restrict__ Zp, u16* __restrict__ Zi)
{
  u32 idx = blockIdx.x*256 + threadIdx.x;
  u32 h = idx>>16, rem = idx&65535u;
  const float* zp = Zp + ((size_t)h<<19);
  float s = 0.f;
  #pragma unroll
  for (int q=0;q<8;q++) s += zp[((size_t)q<<16) + rem];
  Zi[idx] = f2b(1.f/s);
}

// ---------------------------------------------------------------------------
// Triangle pass 2: A = exp2(s')*Zinv; out[i,n,:] = A·V_n; gate.
// K pre-scaled (no scale mul); Zi in bf16 (zi regs 64->32, VGPR under the
// 64 bracket -> 2x theoretical wave residency). Register A-handoff: lane
// (g,l) holds attention row i=l; j is PV's reduction axis so its order is
// free -> PV consumes the lane's own pk regs; V^T read with permuted-j
// (2x 8B LDS reads, 2-way banks = free). LDS = VtS only (16.9 KB).
// ---------------------------------------------------------------------------
__global__ __launch_bounds__(256)
void tri_pass2(const u16* __restrict__ Qall, const u16* __restrict__ Kall,
               const u16* __restrict__ VTall, const u16* __restrict__ Zinv,
               const u16* __restrict__ Gall, u16* __restrict__ O)
{
  int wid = threadIdx.x>>6, lane = threadIdx.x&63;
  int bx = blockIdx.x;
  int nc = bx & 127, ib = (bx>>7)&3, h = bx>>9;
  int i0 = (ib<<6) + (wid<<4);
  int lr = lane&15, ko=(lane>>4)<<3;
  int cl = lane&15, rq=(lane>>4)<<2;
  int g4 = (lane>>4)<<2;                       // 4*g for permuted V reads
  const u16* Q  = Qall + (size_t)h*2097152;
  const u16* Kp = Kall + (size_t)h*2097152;
  const u16* VT = VTall + (size_t)h*2097152;
  const u16* G  = Gall + (size_t)h*2097152;
  const u16* Zh = Zinv + ((size_t)h<<16);
  __shared__ alignas(16) u16 VtS[32][264];     // V^T tile [c][j] (shared)
  int n0 = nc<<1;
  // staging geometry: thread -> (row = t>>3, 64B segment = t&7); 4x uint4 each
  int sr = threadIdx.x>>3, sg = (threadIdx.x&7)<<5;   // sg in elements
  const uint4* s0 = (const uint4*)(VT + ((size_t)n0<<13) + sr*256 + sg);
  uint4 a0=s0[0], a1=s0[1], a2=s0[2], a3=s0[3];
  // Zi preload (bf16): lane covers (i = i0+cl, j = jt*16+rq+0..3) -> uint2
  uint2 zi[16];
  #pragma unroll
  for (int jt=0;jt<16;jt++)
    zi[jt] = *(const uint2*)&Zh[((size_t)(i0+cl)<<8) + (jt<<4) + rq];
  uint4* dS = (uint4*)&VtS[sr][sg];
  dS[0]=a0; dS[1]=a1; dS[2]=a2; dS[3]=a3;
  __syncthreads();                                    // VtS(n0) ready
  // issue-early: prefetch VT(n0+1) into regs; drained only at the WAR barrier
  const uint4* s1 = (const uint4*)(VT + ((size_t)(n0+1)<<13) + sr*256 + sg);
  uint4 b0_=s1[0], b1_=s1[1], b2_=s1[2], b3_=s1[3];
  union U8 { uint4 u; v8s v; };
  #pragma unroll
  for (int nn=0; nn<2; nn++){
    int n = n0 + nn;
    v8s qf = *(const v8s*)(Q + ((size_t)n*256 + i0 + lr)*32 + ko);
    uint2 pk[16];
    #pragma unroll
    for (int jt=0;jt<16;jt++){
      v8s kf = *(const v8s*)(Kp + ((size_t)n*256 + (jt<<4)+lr)*32 + ko);
      v4f z={0.f,0.f,0.f,0.f};
      v4f s = MFMA(kf, qf, z);     // S'^T (pre-scaled): lane -> (i, j-quad)
      u32 za = zi[jt].x, zb = zi[jt].y;
      pk[jt].x = f2b2(ex2(s[0])*blo(za), ex2(s[1])*bhi(za));
      pk[jt].y = f2b2(ex2(s[2])*blo(zb), ex2(s[3])*bhi(zb));
    }
    // PV: out[i,c] = sum_j A[i,j]*VT[c][j]; k-slot order within each 32-j
    // chunk permuted so lane (g,l) supplies its own registers as A-operand.
    v4f o0={0.f,0.f,0.f,0.f}, o1={0.f,0.f,0.f,0.f};
    #pragma unroll
    for (int kc=0;kc<8;kc++){
      U8 A_, B0, B1;
      A_.u.x = pk[2*kc].x;   A_.u.y = pk[2*kc].y;
      A_.u.z = pk[2*kc+1].x; A_.u.w = pk[2*kc+1].y;
      uint2 v0a = *(const uint2*)&VtS[lr][kc*32 + g4];
      uint2 v0b = *(const uint2*)&VtS[lr][kc*32 + g4 + 16];
      uint2 v1a = *(const uint2*)&VtS[16+lr][kc*32 + g4];
      uint2 v1b = *(const uint2*)&VtS[16+lr][kc*32 + g4 + 16];
      B0.u.x=v0a.x; B0.u.y=v0a.y; B0.u.z=v0b.x; B0.u.w=v0b.y;
      B1.u.x=v1a.x; B1.u.y=v1a.y; B1.u.z=v1b.x; B1.u.w=v1b.y;
      o0 = MFMA(A_.v, B0.v, o0);
      o1 = MFMA(A_.v, B1.v, o1);
    }
    #pragma unroll
    for (int r=0;r<4;r++){
      size_t grow = (((size_t)n<<8) + (i0+rq+r))<<5;   // [n][i][c] gate layout
      size_t obase = ((size_t)(i0+rq+r)*256 + n)*128 + h*32;
      float g0 = b2f(G[grow + cl]);
      float g1 = b2f(G[grow + 16 + cl]);
      float sg0 = frcp(1.f + ex2(-g0*L2E));
      float sg1 = frcp(1.f + ex2(-g1*L2E));
      O[obase + cl]      = f2b(o0[r] * sg0);
      O[obase + 16 + cl] = f2b(o1[r] * sg1);
    }
    if (nn==0){
      __syncthreads();                                // WAR: VtS(n0) consumed
      dS[0]=b0_; dS[1]=b1_; dS[2]=b2_; dS[3]=b3_;     // write-late
      __syncthreads();                                // RAW: VtS(n1) ready
    }
  }
}

// ---------------------------------------------------------------------------
extern "C" void kernel_launch(void* const* d_in, const int* in_sizes, int n_in,
                              void* d_out, int out_size, void* d_ws, size_t ws_size,
                              hipStream_t stream) {
  (void)in_sizes; (void)n_in; (void)out_size; (void)ws_size;
  char* ws = (char*)d_ws;
  constexpr size_t OFF_MSAC  = 0;           //  4 MiB
  constexpr size_t OFF_QKV   = 4194304;     // 12 MiB
  constexpr size_t OFF_B1    = 16777216;    //  4 MiB
  constexpr size_t OFF_MSA1  = 25165824;    //  4 MiB
  constexpr size_t OFF_WCVT  = 29360128;    //  1.29 MiB
  constexpr size_t OFF_MEAN  = 30670848;    //  128 KiB
  constexpr size_t OFF_LEFT  = 30801920;    //  64 KiB
  constexpr size_t OFF_WALL  = 30867456;    //  128 KiB
  constexpr size_t OFF_BALL  = 30998528;    //  1 KiB
  constexpr size_t OFF_PAIRN = 31457280;    // 16 MiB
  constexpr size_t OFF_QKVG  = 50331648;    // 64 MiB (Q|K'|V^T|G × 4 heads)
  constexpr size_t OFF_ZP    = 117440512;   //  8 MiB
  constexpr size_t OFF_ZI    = 125829120;   //  512 KiB (bf16 now)
  constexpr size_t OFF_GATED = 126877696;   // 16 MiB (pairT aliases its head)

  u16* msaC  = (u16*)(ws + OFF_MSAC);
  u16* qkv   = (u16*)(ws + OFF_QKV);
  u16* b1    = (u16*)(ws + OFF_B1);
  u16* msa1  = (u16*)(ws + OFF_MSA1);
  u16* wc    = (u16*)(ws + OFF_WCVT);
  u16* meanr = (u16*)(ws + OFF_MEAN);
  u16* left  = (u16*)(ws + OFF_LEFT);
  u16* Wall  = (u16*)(ws + OFF_WALL);
  u16* ball  = (u16*)(ws + OFF_BALL);
  u16* pairN = (u16*)(ws + OFF_PAIRN);
  u16* qkvg  = (u16*)(ws + OFF_QKVG);
  float* Zp  = (float*)(ws + OFF_ZP);
  u16* Zi    = (u16*)(ws + OFF_ZI);
  u16* gated = (u16*)(ws + OFF_GATED);
  u16* pairT = (u16*)(ws + OFF_GATED);   // alias: dead before tri_pass2 writes gated

  u16* Qall = qkvg;
  u16* Kall = qkvg + 8388608;    // pre-scaled by SC2E
  u16* Vall = qkvg + 16777216;   // stored transposed: [h][n][c][j]
  u16* Gall = qkvg + 25165824;

  float* out_msa  = (float*)d_out;
  float* out_pair = (float*)d_out + 2097152;

  static const u32 WOFF[26] = {
    0, 196608, 197376, 262912, 263168, 459776, 460544, 526080,
    526336, 559104, 559232, 559488, 559744, 559872,
    560000, 576384, 576512, 592896, 593024, 609408,
    609536, 625920, 626048, 642432, 642560, 642688 };
  static const u32 WN[26] = {
    196608, 768, 65536, 256, 196608, 768, 65536, 256,
    32768, 128, 256, 256, 128, 128,
    16384, 128, 16384, 128, 16384, 128,
    16384, 128, 16384, 128, 128, 128 };

  const u16* row_Wqkv = wc + WOFF[0];
  const u16* row_bqkv = wc + WOFF[1];
  const u16* row_Wo   = wc + WOFF[2];
  const u16* row_bo   = wc + WOFF[3];
  const u16* col_Wqkv = wc + WOFF[4];
  const u16* col_bqkv = wc + WOFF[5];
  const u16* col_Wo   = wc + WOFF[6];
  const u16* col_bo   = wc + WOFF[7];
  const u16* op_W     = wc + WOFF[8];
  const u16* op_b     = wc + WOFF[9];
  const u16* nm_g     = wc + WOFF[10];
  const u16* nm_b     = wc + WOFF[11];
  const u16* np_g     = wc + WOFF[12];
  const u16* np_b     = wc + WOFF[13];
  const u16* tq_W     = wc + WOFF[14];
  const u16* tq_b     = wc + WOFF[15];
  const u16* tk_W     = wc + WOFF[16];
  const u16* tk_b     = wc + WOFF[17];
  const u16* tv_W     = wc + WOFF[18];
  const u16* tv_b     = wc + WOFF[19];
  const u16* tg_W     = wc + WOFF[20];
  const u16* tg_b     = wc + WOFF[21];
  const u16* to_W     = wc + WOFF[22];
  const u16* to_b     = wc + WOFF[23];
  const u16* tn_g     = wc + WOFF[24];
  const u16* tn_b     = wc + WOFF[25];

  // --- convert f32 inputs to bf16 ---
  cvt_f32<<<2048, 256, 0, stream>>>((const float*)d_in[0], msaC, 524288u);
  Segs segs;
  for (int k = 0; k < 26; k++) { segs.src[k] = d_in[3+k]; segs.off[k] = WOFF[k]; segs.n[k] = WN[k]; }
  cvt_segs<<<640, 256, 0, stream>>>(segs, wc);

  // --- row attention ---
  gemm_t<256,0><<<768, 256, 0, stream>>>(msaC, row_Wqkv, row_bqkv, qkv, 8192, 768);
  row_attn<<<1024, 256, 0, stream>>>(qkv, b1);
  gemm_ln256<0><<<256, 256, 0, stream>>>(b1, row_Wo, row_bo, nm_g, nm_b, msa1);
  // --- column attention ---
  gemm_t<256,0><<<768, 256, 0, stream>>>(msa1, col_Wqkv, col_bqkv, qkv, 8192, 768);
  col_attn<<<256, 256, 0, stream>>>(qkv, b1);
  gemm_ln256<1><<<256, 256, 0, stream>>>(b1, col_Wo, col_bo, nm_g, nm_b, out_msa);
  // --- outer product mean ---
  mean_rows<<<256, 256, 0, stream>>>(out_msa, meanr);
  gemm_t<256,0><<<4, 256, 0, stream>>>(meanr, op_W, op_b, left, 256, 128);
  pair_outer_ln<<<16384, 256, 0, stream>>>((const float*)d_in[1], left, np_g, np_b,
                                           pairN, pairT);
  // --- triangle attention, all heads batched ---
  pack_w<<<256, 256, 0, stream>>>(tq_W, tk_W, tv_W, tg_W, tq_b, tk_b, tv_b, tg_b,
                                  Wall, ball);
  tri_proj<<<512, 256, 0, stream>>>(pairT, Wall, ball, qkvg);
  tri_pass1<<<2048, 256, 0, stream>>>(Qall, Kall, Zp);
  zred<<<1024, 256, 0, stream>>>(Zp, Zi);
  tri_pass2<<<2048, 256, 0, stream>>>(Qall, Kall, Vall, Zi, Gall, gated);
  gemm_ln128_res<<<1024, 256, 0, stream>>>(gated, to_W, to_b, pairN, tn_g, tn_b,
                                           out_pair);
}

// Round 12
// 409.599 us; speedup vs baseline: 1.0211x; 1.0211x over previous
//
#include <hip/hip_runtime.h>

typedef unsigned short u16;
typedef unsigned int   u32;

using v8s = __attribute__((ext_vector_type(8))) short;
using v4f = __attribute__((ext_vector_type(4))) float;

__device__ __forceinline__ float b2f(u16 u){ union{u32 i; float f;} x; x.i=((u32)u)<<16; return x.f; }
__device__ __forceinline__ float blo(u32 u){ union{u32 i; float f;} x; x.i=u<<16; return x.f; }
__device__ __forceinline__ float bhi(u32 u){ union{u32 i; float f;} x; x.i=u&0xffff0000u; return x.f; }
// round-half-up bf16: 0.5-ULP bound like RNE, 2 VALU ops instead of ~9
__device__ __forceinline__ u16 f2b(float f){ union{float f; u32 i;} x; x.f=f; return (u16)((x.i + 0x8000u)>>16); }
__device__ __forceinline__ u32 f2b2(float a,float b){ return (u32)f2b(a) | ((u32)f2b(b)<<16); }

// hardware 2^x (v_exp_f32) with constant pre-fold; rcp instead of IEEE divide
#if __has_builtin(__builtin_amdgcn_exp2f)
__device__ __forceinline__ float ex2(float x){ return __builtin_amdgcn_exp2f(x); }
#else
__device__ __forceinline__ float ex2(float x){ return __expf(x * 0.69314718055994531f); }
#endif
#if __has_builtin(__builtin_amdgcn_rcpf)
__device__ __forceinline__ float frcp(float x){ return __builtin_amdgcn_rcpf(x); }
#else
__device__ __forceinline__ float frcp(float x){ return 1.f/x; }
#endif
#define SC2E 0.25503486f            /* (1/sqrt(32)) * log2(e) */
#define L2E  1.4426950408889634f    /* log2(e) */

#define MFMA(a,b,c) __builtin_amdgcn_mfma_f32_16x16x32_bf16(a,b,c,0,0,0)

// ---------------------------------------------------------------------------
// f32 -> bf16 converters
// ---------------------------------------------------------------------------
__global__ __launch_bounds__(256)
void cvt_f32(const float* __restrict__ src, u16* __restrict__ dst, u32 n4)
{ // n4 = n/4; each thread converts 4
  u32 i = blockIdx.x*256 + threadIdx.x;
  if (i >= n4) return;
  const float4 v = *(const float4*)(src + (size_t)i*4);
  uint2 o = { f2b2(v.x, v.y), f2b2(v.z, v.w) };
  *(uint2*)(dst + (size_t)i*4) = o;
}

struct Segs { const void* src[26]; u32 off[26]; u32 n[26]; };

__global__ __launch_bounds__(256)
void cvt_segs(Segs s, u16* __restrict__ dst)
{
  u32 stride = gridDim.x * 256;
  u32 gid = blockIdx.x*256 + threadIdx.x;
  for (int k = 0; k < 26; k++) {
    const float* sf = (const float*)s.src[k];
    u16* d = dst + s.off[k];
    for (u32 i = gid; i < s.n[k]; i += stride) d[i] = f2b(sf[i]);
  }
}

// ---------------------------------------------------------------------------
// Generic GEMM: C[M,N] = A[M,K] @ B[N,K]^T + bias.  All bf16.  MODE 0 only.
// Wave computes a 32x64 tile. Transposed MFMA (operands swapped) so each
// lane's 4 acc regs are 4 CONSECUTIVE output columns -> packed 8B stores.
// ---------------------------------------------------------------------------
template<int K, int MODE>
__global__ __launch_bounds__(256)
void gemm_t(const u16* __restrict__ A, const u16* __restrict__ B,
            const u16* __restrict__ bias, u16* __restrict__ C,
            int M, int N)
{
  int wid = threadIdx.x >> 6, lane = threadIdx.x & 63;
  int tiles_n = N >> 6;
  int t = blockIdx.x*4 + wid;
  if (t >= (M>>5)*tiles_n) return;
  int tm = t / tiles_n, tn = t % tiles_n;
  int m0 = tm<<5, n0 = tn<<6;
  int lr = lane & 15, ko = (lane>>4)<<3;
  const u16* ap = A + (size_t)(m0+lr)*K + ko;
  const u16* bp = B + (size_t)(n0+lr)*K + ko;
  v4f acc[2][4];
  #pragma unroll
  for (int x=0;x<2;x++)
    #pragma unroll
    for (int y=0;y<4;y++){ v4f z={0.f,0.f,0.f,0.f}; acc[x][y]=z; }
  #pragma unroll
  for (int kc = 0; kc < K; kc += 32) {
    v8s a0 = *(const v8s*)(ap + kc);
    v8s a1 = *(const v8s*)(ap + (size_t)16*K + kc);
    #pragma unroll
    for (int y=0;y<4;y++){
      v8s b = *(const v8s*)(bp + (size_t)(y<<4)*K + kc);
      acc[0][y]=MFMA(b,a0,acc[0][y]);   // transposed: D'[n][m]
      acc[1][y]=MFMA(b,a1,acc[1][y]);
    }
  }
  // D' layout: acc[x][y][r] = C[row = m0+x*16+cl][col = n0+y*16+rq+r]
  int cl = lane&15, rq=(lane>>4)<<2;
  #pragma unroll
  for (int y=0;y<4;y++){
    u32 bl = *(const u32*)(bias + n0 + (y<<4) + rq);
    u32 bh = *(const u32*)(bias + n0 + (y<<4) + rq + 2);
    float bv0=blo(bl), bv1=bhi(bl), bv2=blo(bh), bv3=bhi(bh);
    #pragma unroll
    for (int x=0;x<2;x++){
      float v0 = acc[x][y][0] + bv0;
      float v1 = acc[x][y][1] + bv1;
      float v2 = acc[x][y][2] + bv2;
      float v3 = acc[x][y][3] + bv3;
      uint2 pk = { f2b2(v0,v1), f2b2(v2,v3) };
      int row = m0 + (x<<4) + cl;
      int col = n0 + (y<<4) + rq;         // 4-aligned
      *(uint2*)&C[(size_t)row*N + col] = pk;
    }
  }
}

// ---------------------------------------------------------------------------
// Fused GEMM(8192x256, K=256) + LayerNorm over the 256-col rows.
// ---------------------------------------------------------------------------
template<int F32OUT>
__global__ __launch_bounds__(256)
void gemm_ln256(const u16* __restrict__ A, const u16* __restrict__ B,
                const u16* __restrict__ bias, const u16* __restrict__ gg,
                const u16* __restrict__ bb, void* __restrict__ Yv)
{
  int wid = threadIdx.x >> 6, lane = threadIdx.x & 63;
  int m0 = blockIdx.x << 5, n0 = wid << 6;
  int lr = lane & 15, ko = (lane>>4)<<3;
  const u16* ap = A + (size_t)(m0+lr)*256 + ko;
  const u16* bp = B + (size_t)(n0+lr)*256 + ko;
  v4f acc[2][4];
  #pragma unroll
  for (int x=0;x<2;x++)
    #pragma unroll
    for (int y=0;y<4;y++){ v4f z={0.f,0.f,0.f,0.f}; acc[x][y]=z; }
  #pragma unroll
  for (int kc = 0; kc < 256; kc += 32) {
    v8s a0 = *(const v8s*)(ap + kc);
    v8s a1 = *(const v8s*)(ap + (size_t)16*256 + kc);
    #pragma unroll
    for (int y=0;y<4;y++){
      v8s b = *(const v8s*)(bp + (size_t)(y<<4)*256 + kc);
      acc[0][y]=MFMA(b,a0,acc[0][y]);
      acc[1][y]=MFMA(b,a1,acc[1][y]);
    }
  }
  int cl = lane&15, rq=(lane>>4)<<2;
  __shared__ alignas(16) u16 stage[32][264];   // padded: ~2-way banks
  #pragma unroll
  for (int y=0;y<4;y++){
    u32 bl = *(const u32*)(bias + n0 + (y<<4) + rq);
    u32 bh = *(const u32*)(bias + n0 + (y<<4) + rq + 2);
    float bv0=blo(bl), bv1=bhi(bl), bv2=blo(bh), bv3=bhi(bh);
    #pragma unroll
    for (int x=0;x<2;x++){
      uint2 pk = { f2b2(acc[x][y][0]+bv0, acc[x][y][1]+bv1),
                   f2b2(acc[x][y][2]+bv2, acc[x][y][3]+bv3) };
      *(uint2*)&stage[(x<<4)+cl][n0 + (y<<4) + rq] = pk;
    }
  }
  __syncthreads();
  // LN: wave handles rows wid*8 .. wid*8+7 (identical math to ln256)
  for (int rr = 0; rr < 8; rr++){
    int row = wid*8 + rr;
    u32 a = *(const u32*)&stage[row][lane*2];
    u32 c = *(const u32*)&stage[row][128 + lane*2];
    float v0=blo(a), v1=bhi(a), v2=blo(c), v3=bhi(c);
    float s = v0+v1+v2+v3;
    for (int m=1;m<64;m<<=1) s += __shfl_xor(s,m,64);
    float mean = s * (1.f/256.f);
    float d0=v0-mean,d1=v1-mean,d2=v2-mean,d3=v3-mean;
    float qs = d0*d0+d1*d1+d2*d2+d3*d3;
    for (int m=1;m<64;m<<=1) qs += __shfl_xor(qs,m,64);
    float rstd = rsqrtf(qs*(1.f/256.f) + 1e-5f);
    u32 g0=*(const u32*)(gg+lane*2), g1=*(const u32*)(gg+128+lane*2);
    u32 b0=*(const u32*)(bb+lane*2), b1=*(const u32*)(bb+128+lane*2);
    float w0 = d0*rstd*blo(g0)+blo(b0), w1 = d1*rstd*bhi(g0)+bhi(b0);
    float w2 = d2*rstd*blo(g1)+blo(b1), w3 = d3*rstd*bhi(g1)+bhi(b1);
    if (F32OUT){
      float* y = (float*)Yv + (size_t)(m0+row)*256;
      float2 p0 = {w0,w1}, p1 = {w2,w3};
      *(float2*)(y + lane*2)       = p0;
      *(float2*)(y + 128 + lane*2) = p1;
    } else {
      u16* y = (u16*)Yv + (size_t)(m0+row)*256;
      *(u32*)(y+lane*2)     = f2b2(w0,w1);
      *(u32*)(y+128+lane*2) = f2b2(w2,w3);
    }
  }
}

// ---------------------------------------------------------------------------
// Fused GEMM(65536x128, K=128) + residual LayerNorm (X + R) -> f32 out_pair.
// ---------------------------------------------------------------------------
__global__ __launch_bounds__(256)
void gemm_ln128_res(const u16* __restrict__ A, const u16* __restrict__ B,
                    const u16* __restrict__ bias, const u16* __restrict__ R,
                    const u16* __restrict__ gg, const u16* __restrict__ bb,
                    float* __restrict__ Y)
{
  int wid = threadIdx.x >> 6, lane = threadIdx.x & 63;
  int t = blockIdx.x*4 + wid;          // 4096 total, exact
  int tm = t >> 1, tn = t & 1;
  int m0 = tm << 5, n0 = tn << 6;
  int mB = blockIdx.x << 6;            // block row base (64 rows)
  int lr = lane & 15, ko = (lane>>4)<<3;
  const u16* ap = A + (size_t)(m0+lr)*128 + ko;
  const u16* bp = B + (size_t)(n0+lr)*128 + ko;
  v4f acc[2][4];
  #pragma unroll
  for (int x=0;x<2;x++)
    #pragma unroll
    for (int y=0;y<4;y++){ v4f z={0.f,0.f,0.f,0.f}; acc[x][y]=z; }
  #pragma unroll
  for (int kc = 0; kc < 128; kc += 32) {
    v8s a0 = *(const v8s*)(ap + kc);
    v8s a1 = *(const v8s*)(ap + (size_t)16*128 + kc);
    #pragma unroll
    for (int y=0;y<4;y++){
      v8s b = *(const v8s*)(bp + (size_t)(y<<4)*128 + kc);
      acc[0][y]=MFMA(b,a0,acc[0][y]);
      acc[1][y]=MFMA(b,a1,acc[1][y]);
    }
  }
  int cl = lane&15, rq=(lane>>4)<<2;
  __shared__ alignas(16) u16 stage[64][136];   // padded: ~2-way banks
  int rbase = m0 - mB;                         // 0 or 32
  #pragma unroll
  for (int y=0;y<4;y++){
    u32 bl = *(const u32*)(bias + n0 + (y<<4) + rq);
    u32 bh = *(const u32*)(bias + n0 + (y<<4) + rq + 2);
    float bv0=blo(bl), bv1=bhi(bl), bv2=blo(bh), bv3=bhi(bh);
    #pragma unroll
    for (int x=0;x<2;x++){
      uint2 pk = { f2b2(acc[x][y][0]+bv0, acc[x][y][1]+bv1),
                   f2b2(acc[x][y][2]+bv2, acc[x][y][3]+bv3) };
      *(uint2*)&stage[rbase + (x<<4)+cl][n0 + (y<<4) + rq] = pk;
    }
  }
  __syncthreads();
  // LN(X+R): wave handles rows wid*16 .. wid*16+15 (identical to ln_res128_f32)
  for (int rr = 0; rr < 16; rr++){
    int r_loc = wid*16 + rr;
    int row = mB + r_loc;
    u32 ux = *(const u32*)&stage[r_loc][lane*2];
    u32 ur = *(const u32*)(R + (size_t)row*128 + lane*2);
    float v0 = blo(ux)+blo(ur), v1 = bhi(ux)+bhi(ur);
    float s = v0+v1;
    for (int m=1;m<64;m<<=1) s += __shfl_xor(s,m,64);
    float mean = s * (1.f/128.f);
    float d0=v0-mean, d1=v1-mean;
    float qs = d0*d0+d1*d1;
    for (int m=1;m<64;m<<=1) qs += __shfl_xor(qs,m,64);
    float rstd = rsqrtf(qs*(1.f/128.f)+1e-5f);
    u32 ug = *(const u32*)(gg + lane*2), ub = *(const u32*)(bb + lane*2);
    float2 w = { d0*rstd*blo(ug)+blo(ub), d1*rstd*bhi(ug)+bhi(ub) };
    *(float2*)&Y[(size_t)row*128 + lane*2] = w;
  }
}

// ---------------------------------------------------------------------------
// Triangle projection GEMM: C[r][col] = pairT[r][:] @ Wall[col][:]^T + ball.
// Block = 128 rows; wave = 32 rows, A register-cached, loops all 8 col-tiles.
// K-group output (gg 4..7) is PRE-SCALED by SC2E so tri_pass1/2 compute
// exp2(s) with no per-element scale mul (same 1-rounding error structure).
// ---------------------------------------------------------------------------
__global__ __launch_bounds__(256)
void tri_proj(const u16* __restrict__ A, const u16* __restrict__ B,
              const u16* __restrict__ bias, u16* __restrict__ C)
{
  int wid = threadIdx.x >> 6, lane = threadIdx.x & 63;
  int r0 = blockIdx.x << 7;            // 128 rows per block (512 blocks)
  int rw = r0 + (wid << 5);            // wave rows rw..rw+31
  int lr = lane & 15, ko = (lane>>4)<<3;
  int cl = lane & 15, rq = (lane>>4)<<2;
  int n  = r0 >> 8;                    // n-chunk (block never straddles)
  int j0 = rw & 255;                   // token base within chunk
  // preload A (32 rows x 128) into regs: 2 row-groups x 4 k-chunks
  const u16* ap = A + (size_t)(rw + lr)*128 + ko;
  v8s av[2][4];
  #pragma unroll
  for (int xg=0;xg<2;xg++)
    #pragma unroll
    for (int kq=0;kq<4;kq++)
      av[xg][kq] = *(const v8s*)(ap + (size_t)(xg<<4)*128 + (kq<<5));
  __shared__ alignas(16) u16 stg[4][2][32][40];   // padded rows (20 KB)
  for (int tn=0; tn<8; tn++){
    int n0 = tn<<6;
    const u16* bp = B + (size_t)(n0 + lr)*128 + ko;
    v8s bv[4][4];
    #pragma unroll
    for (int y=0;y<4;y++)
      #pragma unroll
      for (int kq=0;kq<4;kq++)
        bv[y][kq] = *(const v8s*)(bp + (size_t)(y<<4)*128 + (kq<<5));
    v4f acc[2][4];
    #pragma unroll
    for (int xg=0;xg<2;xg++)
      #pragma unroll
      for (int y=0;y<4;y++){ v4f z={0.f,0.f,0.f,0.f}; acc[xg][y]=z; }
    #pragma unroll
    for (int kq=0;kq<4;kq++)
      #pragma unroll
      for (int xg=0;xg<2;xg++)
        #pragma unroll
        for (int y=0;y<4;y++)
          acc[xg][y] = MFMA(bv[y][kq], av[xg][kq], acc[xg][y]);  // D'[col][row]
    // acc[xg][y][r] = C[row = rw + xg*16 + cl][col = n0 + y*16 + rq + r]
    #pragma unroll
    for (int g2=0; g2<2; g2++){
      int gg = (n0>>5) + g2;
      bool isV = (gg>=8) && (gg<12);
      bool isK = (gg>=4) && (gg<8);
      float scl = isK ? SC2E : 1.f;
      u16* sw = &stg[wid][g2][0][0];
      #pragma unroll
      for (int yy=0; yy<2; yy++){
        int y = (g2<<1)+yy;
        u32 bl2 = *(const u32*)(bias + n0 + (y<<4) + rq);
        u32 bh2 = *(const u32*)(bias + n0 + (y<<4) + rq + 2);
        float bb0=blo(bl2), bb1=bhi(bl2), bb2=blo(bh2), bb3=bhi(bh2);
        #pragma unroll
        for (int xg=0;xg<2;xg++){
          float v0=(acc[xg][y][0]+bb0)*scl, v1=(acc[xg][y][1]+bb1)*scl;
          float v2=(acc[xg][y][2]+bb2)*scl, v3=(acc[xg][y][3]+bb3)*scl;
          int tok=(xg<<4)+cl, cb=(yy<<4)+rq;
          if (!isV){
            uint2 pk = { f2b2(v0,v1), f2b2(v2,v3) };
            *(uint2*)(sw + tok*40 + cb) = pk;        // [tok][c]
          } else {
            sw[(cb+0)*40+tok]=f2b(v0);               // [c][tok] (transpose)
            sw[(cb+1)*40+tok]=f2b(v1);
            sw[(cb+2)*40+tok]=f2b(v2);
            sw[(cb+3)*40+tok]=f2b(v3);
          }
        }
      }
      // wave-internal LDS RAW: backend inserts lgkmcnt wait (same object)
      if (!isV){
        u16* dst = C + (size_t)gg*2097152 + (size_t)rw*32;   // 2KB contiguous
        #pragma unroll
        for (int q=0;q<2;q++){
          int row = (q<<4) + (lane>>2), c8 = (lane&3)<<3;
          uint4 d = *(const uint4*)(sw + row*40 + c8);
          *(uint4*)(dst + (q<<9) + (lane<<3)) = d;
        }
      } else {
        int cr0 = lane>>2, off=(lane&3)<<3;
        #pragma unroll
        for (int q=0;q<2;q++){
          int cr = (q<<4)+cr0;
          uint4 d = *(const uint4*)(sw + cr*40 + off);
          *(uint4*)(C + (size_t)gg*2097152 + ((size_t)n<<13) + ((size_t)cr<<8) + j0 + off) = d;
        }
      }
    }
  }
}

// ---------------------------------------------------------------------------
// Row attention core: block = (bs,h,si). Input QKV [8192][768] (Q|K|V of 256).
// ---------------------------------------------------------------------------
__global__ __launch_bounds__(256)
void row_attn(const u16* __restrict__ QKV, u16* __restrict__ Out)
{
  int si = blockIdx.x & 3, h = (blockIdx.x>>2) & 7, bs = blockIdx.x >> 5;
  int wid = threadIdx.x >> 6, lane = threadIdx.x & 63;
  int lr = lane & 15, ko = (lane>>4)<<3;
  int cl = lane & 15, rq = (lane>>4)<<2;
  __shared__ alignas(16) u16 VtS[32][264];      // V^T  [c][j]
  __shared__ alignas(16) u16 AsS[4][16][264];   // per-wave attn strip [i][j]
  const u16* base = QKV + (size_t)bs * 256 * 768;
  for (int e = threadIdx.x; e < 4096; e += 256) {
    int j = e >> 4, cu = e & 15;
    u32 v = *(const u32*)(base + (size_t)j*768 + 512 + h*32 + cu*2);
    VtS[cu*2][j]   = (u16)(v & 0xffffu);
    VtS[cu*2+1][j] = (u16)(v >> 16);
  }
  __syncthreads();
  int i0 = si*64 + wid*16;
  v8s a = *(const v8s*)(base + (size_t)(i0+lr)*768 + h*32 + ko);
  v4f s[16];
  #pragma unroll
  for (int jt = 0; jt < 16; jt++) {
    v8s b = *(const v8s*)(base + (size_t)(jt*16+lr)*768 + 256 + h*32 + ko);
    v4f z = {0.f,0.f,0.f,0.f};
    s[jt] = MFMA(a, b, z);
  }
  float part[4] = {0.f,0.f,0.f,0.f};
  #pragma unroll
  for (int jt = 0; jt < 16; jt++)
    #pragma unroll
    for (int r = 0; r < 4; r++) {
      float e = ex2(s[jt][r] * SC2E);
      s[jt][r] = e;
      part[r] += e;
    }
  #pragma unroll
  for (int r = 0; r < 4; r++) {
    part[r] += __shfl_xor(part[r], 1, 64);
    part[r] += __shfl_xor(part[r], 2, 64);
    part[r] += __shfl_xor(part[r], 4, 64);
    part[r] += __shfl_xor(part[r], 8, 64);
    part[r] = frcp(part[r]);
  }
  #pragma unroll
  for (int jt = 0; jt < 16; jt++)
    #pragma unroll
    for (int r = 0; r < 4; r++)
      AsS[wid][rq+r][jt*16+cl] = f2b(s[jt][r] * part[r]);
  __syncthreads();
  v4f o0={0.f,0.f,0.f,0.f}, o1={0.f,0.f,0.f,0.f};
  #pragma unroll
  for (int kc = 0; kc < 8; kc++) {
    v8s av = *(const v8s*)&AsS[wid][lr][kc*32 + ko];
    v8s b0 = *(const v8s*)&VtS[lr][kc*32 + ko];
    v8s b1 = *(const v8s*)&VtS[16+lr][kc*32 + ko];
    o0 = MFMA(av, b0, o0);
    o1 = MFMA(av, b1, o1);
  }
  u16* orow = Out + ((size_t)(bs*256) + i0)*256 + h*32;
  #pragma unroll
  for (int r = 0; r < 4; r++) {
    orow[(size_t)(rq+r)*256 + cl]      = f2b(o0[r]);
    orow[(size_t)(rq+r)*256 + 16 + cl] = f2b(o1[r]);
  }
}

// ---------------------------------------------------------------------------
// Column attention core: block = n. 32 tokens (s axis), 8 heads. thread=(h,i).
// ---------------------------------------------------------------------------
__global__ __launch_bounds__(256)
void col_attn(const u16* __restrict__ QKV, u16* __restrict__ Out)
{
  int n = blockIdx.x;
  __shared__ alignas(16) u16 T[32][776];
  for (int e = threadIdx.x; e < 32*384; e += 256) {
    int s = e / 384, u = e % 384;
    *(u32*)&T[s][u*2] = *(const u32*)(QKV + ((size_t)s*256 + n)*768 + u*2);
  }
  __syncthreads();
  int h = threadIdx.x >> 5, i = threadIdx.x & 31;
  float q[32];
  #pragma unroll
  for (int cu = 0; cu < 4; cu++) {
    v8s qv = *(const v8s*)&T[i][h*32 + cu*8];
    #pragma unroll
    for (int t2 = 0; t2 < 8; t2++) q[cu*8+t2] = b2f((u16)qv[t2]);
  }
  float sj[32];
  float Z = 0.f;
  #pragma unroll 4
  for (int j = 0; j < 32; j++) {
    float acc = 0.f;
    #pragma unroll
    for (int cu = 0; cu < 4; cu++) {
      v8s kv = *(const v8s*)&T[j][256 + h*32 + cu*8];
      #pragma unroll
      for (int t2 = 0; t2 < 8; t2++) acc += q[cu*8+t2] * b2f((u16)kv[t2]);
    }
    sj[j] = ex2(acc * SC2E);
    Z += sj[j];
  }
  float zi = frcp(Z);
  float o[32];
  #pragma unroll
  for (int c = 0; c < 32; c++) o[c] = 0.f;
  #pragma unroll 4
  for (int j = 0; j < 32; j++) {
    float a = sj[j] * zi;
    #pragma unroll
    for (int cu = 0; cu < 4; cu++) {
      v8s vv = *(const v8s*)&T[j][512 + h*32 + cu*8];
      #pragma unroll
      for (int t2 = 0; t2 < 8; t2++) o[cu*8+t2] += a * b2f((u16)vv[t2]);
    }
  }
  u16* orow = Out + ((size_t)i*256 + n)*256 + h*32;
  #pragma unroll
  for (int cu = 0; cu < 16; cu++)
    *(u32*)&orow[cu*2] = f2b2(o[cu*2], o[cu*2+1]);
}

// ---------------------------------------------------------------------------
// mean over s of final msa (f32) -> Mean[n][c] bf16
// ---------------------------------------------------------------------------
__global__ __launch_bounds__(256)
void mean_rows(const float* __restrict__ M2, u16* __restrict__ Mean)
{
  int n = blockIdx.x, c = threadIdx.x;
  float s = 0.f;
  for (int ss = 0; ss < 32; ss++) s += M2[((size_t)ss*256 + n)*256 + c];
  Mean[(size_t)n*256 + c] = f2b(s * 0.03125f);
}

// ---------------------------------------------------------------------------
// pairN = LN(pair_f32 + outer(left,left)). wave per row (i,j). bf16 out.
// Also writes pairT[j*256+i] (transposed copy) for the projection GEMM.
// ---------------------------------------------------------------------------
__global__ __launch_bounds__(256)
void pair_outer_ln(const float* __restrict__ Pair, const u16* __restrict__ Left,
                   const u16* __restrict__ gg, const u16* __restrict__ bb,
                   u16* __restrict__ PairN, u16* __restrict__ PairT)
{
  int row = blockIdx.x*4 + (threadIdx.x>>6), lane = threadIdx.x & 63;
  int i = row >> 8, j = row & 255;
  float p0 = Pair[(size_t)row*128 + lane*2];
  float p1 = Pair[(size_t)row*128 + lane*2 + 1];
  u32 ul = *(const u32*)(Left + (size_t)i*128 + lane*2);
  u32 ur = *(const u32*)(Left + (size_t)j*128 + lane*2);
  float v0 = p0 + blo(ul)*blo(ur);
  float v1 = p1 + bhi(ul)*bhi(ur);
  float s = v0+v1;
  for (int m=1;m<64;m<<=1) s += __shfl_xor(s,m,64);
  float mean = s * (1.f/128.f);
  float d0=v0-mean, d1=v1-mean;
  float qs = d0*d0+d1*d1;
  for (int m=1;m<64;m<<=1) qs += __shfl_xor(qs,m,64);
  float rstd = rsqrtf(qs*(1.f/128.f)+1e-5f);
  u32 ug = *(const u32*)(gg + lane*2), ub = *(const u32*)(bb + lane*2);
  u32 pk = f2b2(d0*rstd*blo(ug)+blo(ub), d1*rstd*bhi(ug)+bhi(ub));
  *(u32*)&PairN[(size_t)row*128 + lane*2] = pk;
  *(u32*)&PairT[((size_t)j*256 + i)*128 + lane*2] = pk;
}

// ---------------------------------------------------------------------------
// Pack combined triangle weights: Wall[512][128]; ball[512].
// ---------------------------------------------------------------------------
__global__ __launch_bounds__(256)
void pack_w(const u16* __restrict__ tq_W, const u16* __restrict__ tk_W,
            const u16* __restrict__ tv_W, const u16* __restrict__ tg_W,
            const u16* __restrict__ tq_b, const u16* __restrict__ tk_b,
            const u16* __restrict__ tv_b, const u16* __restrict__ tg_b,
            u16* __restrict__ Wall, u16* __restrict__ ball)
{
  int idx = blockIdx.x*256 + threadIdx.x;   // 65536 total
  int r = idx>>7, c = idx&127;
  int part = r>>7, hr = r&127;
  const u16* W = (part==0)? tq_W : (part==1)? tk_W : (part==2)? tv_W : tg_W;
  Wall[idx] = W[(size_t)hr*128 + c];
  if (idx < 512) {
    int p2 = idx>>7, hr2 = idx&127;
    const u16* bsrc = (p2==0)? tq_b : (p2==1)? tk_b : (p2==2)? tv_b : tg_b;
    ball[idx] = bsrc[hr2];
  }
}

// ---------------------------------------------------------------------------
// Triangle pass 1 (all heads): Zp[h][nh][i][j] = sum_{n in chunk} exp2(q·k')
// (K pre-scaled by SC2E at tri_proj -> no per-element scale mul here.)
// ---------------------------------------------------------------------------
__global__ __launch_bounds__(256)
void tri_pass1(const u16* __restrict__ Qall, const u16* __restrict__ Kall,
               float* __restrict__ Zp)
{
  int wid = threadIdx.x>>6, lane = threadIdx.x&63;
  int bx = blockIdx.x;
  int jb = bx & 3, it = (bx>>2)&15, nh = (bx>>6)&7, h = bx>>9;
  int i0 = it<<4, j0 = (jb<<6) + (wid<<4);
  int lr = lane&15, ko=(lane>>4)<<3;
  const u16* qp = Qall + (size_t)h*2097152 + ((size_t)(nh<<5)*256 + i0 + lr)*32 + ko;
  const u16* kp = Kall + (size_t)h*2097152 + ((size_t)(nh<<5)*256 + j0 + lr)*32 + ko;
  float Z[4] = {0.f,0.f,0.f,0.f};
  #pragma unroll
  for (int g=0;g<4;g++){
    v8s qa[8], kb[8];
    #pragma unroll
    for (int t=0;t<8;t++){
      qa[t] = *(const v8s*)(qp + (size_t)(g*8+t)*8192);
      kb[t] = *(const v8s*)(kp + (size_t)(g*8+t)*8192);
    }
    #pragma unroll
    for (int t=0;t<8;t++){
      v4f z = {0.f,0.f,0.f,0.f};
      v4f s = MFMA(qa[t],kb[t],z);
      #pragma unroll
      for (int r=0;r<4;r++) Z[r] += ex2(s[r]);
    }
  }
  int cl=lane&15, rq=(lane>>4)<<2;
  float* zr = Zp + ((size_t)h<<19) + ((size_t)nh<<16);
  #pragma unroll
  for (int r=0;r<4;r++)
    zr[(size_t)(i0+rq+r)*256 + j0+cl] = Z[r];
}

// Zi16[h][ij] = bf16( 1 / sum_nh Zp[h][nh][ij] )
__global__ __launch_bounds__(256)
void zred(const float* __restrict__ Zp, u16* __restrict__ Zi)
{
  u32 idx = blockIdx.x*256 + threadIdx.x;
  u32 h = idx>>16, rem = idx&65535u;
  const float* zp = Zp + ((size_t)h<<19);
  float s = 0.f;
  #pragma unroll
  for (int q=0;q<8;q++) s += zp[((size_t)q<<16) + rem];
  Zi[idx] = f2b(1.f/s);
}

// ---------------------------------------------------------------------------
// Triangle pass 2: A = exp2(s')*Zinv; out[i,n,:] = A·V_n; gate.
// 4 n-TILES PER BLOCK (grid 1024): amortizes the 32KB/block Zi preload over
// 4 n (halves Zi L2 traffic), halves block launch/drain overhead, deepens
// the V prefetch pipeline (single reg buffer rotates n+1 while computing n).
// K pre-scaled (no scale mul); Zi bf16. Register A-handoff: lane (g,l)
// holds attention row i=l; j is PV's reduction axis so its order is free ->
// PV consumes the lane's own pk regs; V^T read with permuted-j (2x 8B LDS
// reads, 2-way banks = free). LDS = VtS only (16.9 KB).
// ---------------------------------------------------------------------------
__global__ __launch_bounds__(256)
void tri_pass2(const u16* __restrict__ Qall, const u16* __restrict__ Kall,
               const u16* __restrict__ VTall, const u16* __restrict__ Zinv,
               const u16* __restrict__ Gall, u16* __restrict__ O)
{
  int wid = threadIdx.x>>6, lane = threadIdx.x&63;
  int bx = blockIdx.x;
  int nc = bx & 63, ib = (bx>>6)&3, h = bx>>8;
  int i0 = (ib<<6) + (wid<<4);
  int lr = lane&15, ko=(lane>>4)<<3;
  int cl = lane&15, rq=(lane>>4)<<2;
  int g4 = (lane>>4)<<2;                       // 4*g for permuted V reads
  const u16* Q  = Qall + (size_t)h*2097152;
  const u16* Kp = Kall + (size_t)h*2097152;
  const u16* VT = VTall + (size_t)h*2097152;
  const u16* G  = Gall + (size_t)h*2097152;
  const u16* Zh = Zinv + ((size_t)h<<16);
  __shared__ alignas(16) u16 VtS[32][264];     // V^T tile [c][j] (shared)
  int n0 = nc<<2;
  // staging geometry: thread -> (row = t>>3, 64B segment = t&7); 4x uint4 each
  int sr = threadIdx.x>>3, sg = (threadIdx.x&7)<<5;   // sg in elements
  const uint4* s0 = (const uint4*)(VT + ((size_t)n0<<13) + sr*256 + sg);
  uint4 a0=s0[0], a1=s0[1], a2=s0[2], a3=s0[3];
  // Zi preload (bf16): lane covers (i = i0+cl, j = jt*16+rq+0..3) -> uint2
  uint2 zi[16];
  #pragma unroll
  for (int jt=0;jt<16;jt++)
    zi[jt] = *(const uint2*)&Zh[((size_t)(i0+cl)<<8) + (jt<<4) + rq];
  uint4* dS = (uint4*)&VtS[sr][sg];
  dS[0]=a0; dS[1]=a1; dS[2]=a2; dS[3]=a3;
  __syncthreads();                                    // VtS(n0) ready
  // issue-early: prefetch VT(n0+1) into regs; drained only at the WAR barrier
  const uint4* s1 = (const uint4*)(VT + ((size_t)(n0+1)<<13) + sr*256 + sg);
  uint4 b0_=s1[0], b1_=s1[1], b2_=s1[2], b3_=s1[3];
  union U8 { uint4 u; v8s v; };
  for (int nn=0; nn<4; nn++){
    int n = n0 + nn;
    v8s qf = *(const v8s*)(Q + ((size_t)n*256 + i0 + lr)*32 + ko);
    uint2 pk[16];
    #pragma unroll
    for (int jt=0;jt<16;jt++){
      v8s kf = *(const v8s*)(Kp + ((size_t)n*256 + (jt<<4)+lr)*32 + ko);
      v4f z={0.f,0.f,0.f,0.f};
      v4f s = MFMA(kf, qf, z);     // S'^T (pre-scaled): lane -> (i, j-quad)
      u32 za = zi[jt].x, zb = zi[jt].y;
      pk[jt].x = f2b2(ex2(s[0])*blo(za), ex2(s[1])*bhi(za));
      pk[jt].y = f2b2(ex2(s[2])*blo(zb), ex2(s[3])*bhi(zb));
    }
    // PV: out[i,c] = sum_j A[i,j]*VT[c][j]; k-slot order within each 32-j
    // chunk permuted so lane (g,l) supplies its own registers as A-operand.
    v4f o0={0.f,0.f,0.f,0.f}, o1={0.f,0.f,0.f,0.f};
    #pragma unroll
    for (int kc=0;kc<8;kc++){
      U8 A_, B0, B1;
      A_.u.x = pk[2*kc].x;   A_.u.y = pk[2*kc].y;
      A_.u.z = pk[2*kc+1].x; A_.u.w = pk[2*kc+1].y;
      uint2 v0a = *(const uint2*)&VtS[lr][kc*32 + g4];
      uint2 v0b = *(const uint2*)&VtS[lr][kc*32 + g4 + 16];
      uint2 v1a = *(const uint2*)&VtS[16+lr][kc*32 + g4];
      uint2 v1b = *(const uint2*)&VtS[16+lr][kc*32 + g4 + 16];
      B0.u.x=v0a.x; B0.u.y=v0a.y; B0.u.z=v0b.x; B0.u.w=v0b.y;
      B1.u.x=v1a.x; B1.u.y=v1a.y; B1.u.z=v1b.x; B1.u.w=v1b.y;
      o0 = MFMA(A_.v, B0.v, o0);
      o1 = MFMA(A_.v, B1.v, o1);
    }
    #pragma unroll
    for (int r=0;r<4;r++){
      size_t grow = (((size_t)n<<8) + (i0+rq+r))<<5;   // [n][i][c] gate layout
      size_t obase = ((size_t)(i0+rq+r)*256 + n)*128 + h*32;
      float g0 = b2f(G[grow + cl]);
      float g1 = b2f(G[grow + 16 + cl]);
      float sg0 = frcp(1.f + ex2(-g0*L2E));
      float sg1 = frcp(1.f + ex2(-g1*L2E));
      O[obase + cl]      = f2b(o0[r] * sg0);
      O[obase + 16 + cl] = f2b(o1[r] * sg1);
    }
    if (nn<3){
      __syncthreads();                                // WAR: VtS(n) consumed
      dS[0]=b0_; dS[1]=b1_; dS[2]=b2_; dS[3]=b3_;     // write-late n+1
      __syncthreads();                                // RAW: VtS(n+1) ready
      if (nn<2){                                      // issue-early n+2
        const uint4* sn = (const uint4*)(VT + ((size_t)(n0+nn+2)<<13) + sr*256 + sg);
        b0_=sn[0]; b1_=sn[1]; b2_=sn[2]; b3_=sn[3];
      }
    }
  }
}

// ---------------------------------------------------------------------------
extern "C" void kernel_launch(void* const* d_in, const int* in_sizes, int n_in,
                              void* d_out, int out_size, void* d_ws, size_t ws_size,
                              hipStream_t stream) {
  (void)in_sizes; (void)n_in; (void)out_size; (void)ws_size;
  char* ws = (char*)d_ws;
  constexpr size_t OFF_MSAC  = 0;           //  4 MiB
  constexpr size_t OFF_QKV   = 4194304;     // 12 MiB
  constexpr size_t OFF_B1    = 16777216;    //  4 MiB
  constexpr size_t OFF_MSA1  = 25165824;    //  4 MiB
  constexpr size_t OFF_WCVT  = 29360128;    //  1.29 MiB
  constexpr size_t OFF_MEAN  = 30670848;    //  128 KiB
  constexpr size_t OFF_LEFT  = 30801920;    //  64 KiB
  constexpr size_t OFF_WALL  = 30867456;    //  128 KiB
  constexpr size_t OFF_BALL  = 30998528;    //  1 KiB
  constexpr size_t OFF_PAIRN = 31457280;    // 16 MiB
  constexpr size_t OFF_QKVG  = 50331648;    // 64 MiB (Q|K'|V^T|G × 4 heads)
  constexpr size_t OFF_ZP    = 117440512;   //  8 MiB
  constexpr size_t OFF_ZI    = 125829120;   //  512 KiB (bf16)
  constexpr size_t OFF_GATED = 126877696;   // 16 MiB (pairT aliases its head)

  u16* msaC  = (u16*)(ws + OFF_MSAC);
  u16* qkv   = (u16*)(ws + OFF_QKV);
  u16* b1    = (u16*)(ws + OFF_B1);
  u16* msa1  = (u16*)(ws + OFF_MSA1);
  u16* wc    = (u16*)(ws + OFF_WCVT);
  u16* meanr = (u16*)(ws + OFF_MEAN);
  u16* left  = (u16*)(ws + OFF_LEFT);
  u16* Wall  = (u16*)(ws + OFF_WALL);
  u16* ball  = (u16*)(ws + OFF_BALL);
  u16* pairN = (u16*)(ws + OFF_PAIRN);
  u16* qkvg  = (u16*)(ws + OFF_QKVG);
  float* Zp  = (float*)(ws + OFF_ZP);
  u16* Zi    = (u16*)(ws + OFF_ZI);
  u16* gated = (u16*)(ws + OFF_GATED);
  u16* pairT = (u16*)(ws + OFF_GATED);   // alias: dead before tri_pass2 writes gated

  u16* Qall = qkvg;
  u16* Kall = qkvg + 8388608;    // pre-scaled by SC2E
  u16* Vall = qkvg + 16777216;   // stored transposed: [h][n][c][j]
  u16* Gall = qkvg + 25165824;

  float* out_msa  = (float*)d_out;
  float* out_pair = (float*)d_out + 2097152;

  static const u32 WOFF[26] = {
    0, 196608, 197376, 262912, 263168, 459776, 460544, 526080,
    526336, 559104, 559232, 559488, 559744, 559872,
    560000, 576384, 576512, 592896, 593024, 609408,
    609536, 625920, 626048, 642432, 642560, 642688 };
  static const u32 WN[26] = {
    196608, 768, 65536, 256, 196608, 768, 65536, 256,
    32768, 128, 256, 256, 128, 128,
    16384, 128, 16384, 128, 16384, 128,
    16384, 128, 16384, 128, 128, 128 };

  const u16* row_Wqkv = wc + WOFF[0];
  const u16* row_bqkv = wc + WOFF[1];
  const u16* row_Wo   = wc + WOFF[2];
  const u16* row_bo   = wc + WOFF[3];
  const u16* col_Wqkv = wc + WOFF[4];
  const u16* col_bqkv = wc + WOFF[5];
  const u16* col_Wo   = wc + WOFF[6];
  const u16* col_bo   = wc + WOFF[7];
  const u16* op_W     = wc + WOFF[8];
  const u16* op_b     = wc + WOFF[9];
  const u16* nm_g     = wc + WOFF[10];
  const u16* nm_b     = wc + WOFF[11];
  const u16* np_g     = wc + WOFF[12];
  const u16* np_b     = wc + WOFF[13];
  const u16* tq_W     = wc + WOFF[14];
  const u16* tq_b     = wc + WOFF[15];
  const u16* tk_W     = wc + WOFF[16];
  const u16* tk_b     = wc + WOFF[17];
  const u16* tv_W     = wc + WOFF[18];
  const u16* tv_b     = wc + WOFF[19];
  const u16* tg_W     = wc + WOFF[20];
  const u16* tg_b     = wc + WOFF[21];
  const u16* to_W     = wc + WOFF[22];
  const u16* to_b     = wc + WOFF[23];
  const u16* tn_g     = wc + WOFF[24];
  const u16* tn_b     = wc + WOFF[25];

  // --- convert f32 inputs to bf16 ---
  cvt_f32<<<2048, 256, 0, stream>>>((const float*)d_in[0], msaC, 524288u);
  Segs segs;
  for (int k = 0; k < 26; k++) { segs.src[k] = d_in[3+k]; segs.off[k] = WOFF[k]; segs.n[k] = WN[k]; }
  cvt_segs<<<640, 256, 0, stream>>>(segs, wc);

  // --- row attention ---
  gemm_t<256,0><<<768, 256, 0, stream>>>(msaC, row_Wqkv, row_bqkv, qkv, 8192, 768);
  row_attn<<<1024, 256, 0, stream>>>(qkv, b1);
  gemm_ln256<0><<<256, 256, 0, stream>>>(b1, row_Wo, row_bo, nm_g, nm_b, msa1);
  // --- column attention ---
  gemm_t<256,0><<<768, 256, 0, stream>>>(msa1, col_Wqkv, col_bqkv, qkv, 8192, 768);
  col_attn<<<256, 256, 0, stream>>>(qkv, b1);
  gemm_ln256<1><<<256, 256, 0, stream>>>(b1, col_Wo, col_bo, nm_g, nm_b, out_msa);
  // --- outer product mean ---
  mean_rows<<<256, 256, 0, stream>>>(out_msa, meanr);
  gemm_t<256,0><<<4, 256, 0, stream>>>(meanr, op_W, op_b, left, 256, 128);
  pair_outer_ln<<<16384, 256, 0, stream>>>((const float*)d_in[1], left, np_g, np_b,
                                           pairN, pairT);
  // --- triangle attention, all heads batched ---
  pack_w<<<256, 256, 0, stream>>>(tq_W, tk_W, tv_W, tg_W, tq_b, tk_b, tv_b, tg_b,
                                  Wall, ball);
  tri_proj<<<512, 256, 0, stream>>>(pairT, Wall, ball, qkvg);
  tri_pass1<<<2048, 256, 0, stream>>>(Qall, Kall, Zp);
  zred<<<1024, 256, 0, stream>>>(Zp, Zi);
  tri_pass2<<<1024, 256, 0, stream>>>(Qall, Kall, Vall, Zi, Gall, gated);
  gemm_ln128_res<<<1024, 256, 0, stream>>>(gated, to_W, to_b, pairN, tn_g, tn_b,
                                           out_pair);
}